// Round 16
// baseline (53.847 us; speedup 1.0000x reference)
//
#include <hip/hip_runtime.h>

#define MARGIN 0.2f
#define EPS_    1e-8f
#define BM 128
#define BKF 32            // K-step in fp32 elements (128 B per row-segment)

typedef __attribute__((ext_vector_type(8))) short short8;
typedef __attribute__((ext_vector_type(4))) float f32x4;

// ---------------------------------------------------------------------------
// Fused GEMM: stages ORIGINAL fp32 X via global_load_lds, converts to bf16 in
// registers at fragment-load time (v_cvt_pk_bf16_f32), computes G = X.X^T
// (bf16 out), and emits fp32 norms from the diagonal tiles' accumulators.
// Upper-tri linear grid + bijective XCD swizzle (T1). 2-phase double-buffered,
// counted vmcnt(8), both-sides XOR swizzle (rule #21).
// G symmetric => transpose-class MFMA layout errors are output-invariant.
// ---------------------------------------------------------------------------
__device__ __forceinline__ unsigned short bf16_1(float x)
{
    union { float f; unsigned u; } v;
    v.f = x;
    return (unsigned short)((v.u + 0x7fffu + ((v.u >> 16) & 1u)) >> 16);
}

__device__ __forceinline__ short8 frag_f32(const char* base, int row, int hi)
{
    const int sw = (row & 7) << 4;
    const f32x4 lo = *(const f32x4*)(base + row * 128 + ((hi * 32) ^ sw));
    const f32x4 hh = *(const f32x4*)(base + row * 128 + ((hi * 32 + 16) ^ sw));
    union { short8 s; unsigned u[4]; } r;
    asm("v_cvt_pk_bf16_f32 %0, %1, %2" : "=v"(r.u[0]) : "v"(lo[0]), "v"(lo[1]));
    asm("v_cvt_pk_bf16_f32 %0, %1, %2" : "=v"(r.u[1]) : "v"(lo[2]), "v"(lo[3]));
    asm("v_cvt_pk_bf16_f32 %0, %1, %2" : "=v"(r.u[2]) : "v"(hh[0]), "v"(hh[1]));
    asm("v_cvt_pk_bf16_f32 %0, %1, %2" : "=v"(r.u[3]) : "v"(hh[2]), "v"(hh[3]));
    return r.s;
}

__global__ __launch_bounds__(256) void gemm_fused(
    const float* __restrict__ xf,    // fp32 X, row stride D*4 bytes
    unsigned short* __restrict__ G,
    float* __restrict__ norms,
    int B, int D, int NB, int ntiles,
    float* __restrict__ ws_total, unsigned int* __restrict__ ws_cnt,
    unsigned int* __restrict__ ws_done)
{
    if (blockIdx.x == 0 && threadIdx.x == 0) {
        *ws_total = 0.0f; *ws_cnt = 0u; *ws_done = 0u;
    }

    // bijective XCD swizzle (m204): tiles sharing bm land on one XCD's L2
    const int q = ntiles >> 3, r8 = ntiles & 7;
    const int xcd = blockIdx.x & 7, idx = blockIdx.x >> 3;
    int lin = ((xcd < r8) ? xcd * (q + 1) : r8 * (q + 1) + (xcd - r8) * q) + idx;

    int bm = 0, rowlen = NB;
    while (lin >= rowlen) { lin -= rowlen; ++bm; --rowlen; }
    const int bn = bm + lin;

    __shared__ char At[2][BM * BKF * 4];       // 2 x 16 KB (fp32 tiles)
    __shared__ char Bt[2][BM * BKF * 4];
    const int tid  = threadIdx.x;
    const int lane = tid & 63;
    const int w    = tid >> 6;
    const int wr   = w >> 1, wc = w & 1;
    const int rowb = D * 4;
    const int l15  = lane & 15;
    const int hi   = lane >> 4;

    f32x4 acc[4][4] = {};

    // pre-swizzled source byte offset within the 128 B row segment
    const int ssw = (((lane & 7) * 16) ^ ((lane >> 3) << 4));

    auto stage = [&](int kk, int p) {
        #pragma unroll
        for (int c4 = 0; c4 < 4; ++c4) {
            const int c = w * 4 + c4;
            const size_t arow = (size_t)bm * BM + c * 8 + (lane >> 3);
            const size_t brow = (size_t)bn * BM + c * 8 + (lane >> 3);
            const char* asrc = (const char*)xf + arow * rowb + kk * (BKF * 4) + ssw;
            const char* bsrc = (const char*)xf + brow * rowb + kk * (BKF * 4) + ssw;
            __builtin_amdgcn_global_load_lds((const unsigned*)asrc,
                (unsigned*)(At[p] + c * 1024 + lane * 16), 16, 0, 0);
            __builtin_amdgcn_global_load_lds((const unsigned*)bsrc,
                (unsigned*)(Bt[p] + c * 1024 + lane * 16), 16, 0, 0);
        }
    };

    const int nk = D / BKF;
    stage(0, 0);
    for (int kk = 0; kk < nk; ++kk) {
        const int p = kk & 1;
        if (kk + 1 < nk) {
            stage(kk + 1, p ^ 1);                              // 8 in flight
            asm volatile("s_waitcnt vmcnt(8)" ::: "memory");   // tile kk ready
        } else {
            asm volatile("s_waitcnt vmcnt(0)" ::: "memory");
        }
        __builtin_amdgcn_s_barrier();
        __builtin_amdgcn_sched_barrier(0);

        short8 a[4], b[4];
        #pragma unroll
        for (int m = 0; m < 4; ++m)
            a[m] = frag_f32(At[p], wr * 64 + m * 16 + l15, hi);
        #pragma unroll
        for (int n = 0; n < 4; ++n)
            b[n] = frag_f32(Bt[p], wc * 64 + n * 16 + l15, hi);
        #pragma unroll
        for (int m = 0; m < 4; ++m)
            #pragma unroll
            for (int n = 0; n < 4; ++n)
                acc[m][n] = __builtin_amdgcn_mfma_f32_16x16x32_bf16(
                    a[m], b[n], acc[m][n], 0, 0, 0);

        asm volatile("s_waitcnt lgkmcnt(0)" ::: "memory");
        __builtin_amdgcn_sched_barrier(0);
        __builtin_amdgcn_s_barrier();
    }

    // norms from the diagonal tiles' fp32 accumulators (row == col lanes)
    if (bm == bn && wr == wc && (l15 >> 2) == hi) {
        #pragma unroll
        for (int m = 0; m < 4; ++m)
            norms[bm * BM + wr * 64 + m * 16 + l15] = acc[m][m][l15 & 3];
    }

    #pragma unroll
    for (int m = 0; m < 4; ++m)
        #pragma unroll
        for (int n = 0; n < 4; ++n)
            #pragma unroll
            for (int j = 0; j < 4; ++j) {
                const int row = bm * BM + wr * 64 + m * 16 + hi * 4 + j;
                const int col = bn * BM + wc * 64 + n * 16 + l15;
                G[(size_t)row * B + col] = bf16_1(acc[m][n][j]);
            }
}

// ---------------------------------------------------------------------------
// phase 2 + finalize: d^2 = n_i + n_j - 2 g_ij (fp32 norms, bf16 G);
// block-reduce + atomics; last block writes the loss.
// ---------------------------------------------------------------------------
__global__ __launch_bounds__(256) void tri_eval(
    const unsigned short* __restrict__ G,
    const float* __restrict__ norms,
    const float* __restrict__ beta,
    const int*   __restrict__ labels,
    const int*   __restrict__ trip,
    int B, int T,
    float*        __restrict__ ws_total,
    unsigned int* __restrict__ ws_cnt,
    unsigned int* __restrict__ ws_done,
    float*        __restrict__ out)
{
    const int i = blockIdx.x * blockDim.x + threadIdx.x;
    float pn = 0.0f;
    int   c  = 0;
    if (i < T) {
        const int t0 = trip[3 * i + 0];
        const int t1 = trip[3 * i + 1];
        const int t2 = trip[3 * i + 2];
        const int r1 = t0 < t1 ? t0 : t1, c1 = t0 < t1 ? t1 : t0;
        const int r2 = t0 < t2 ? t0 : t2, c2 = t0 < t2 ? t2 : t0;
        union { unsigned u; float f; } v1, v2;
        v1.u = (unsigned)G[(size_t)r1 * B + c1] << 16;
        v2.u = (unsigned)G[(size_t)r2 * B + c2] << 16;
        const float n0  = norms[t0];
        const float n1  = norms[t1];
        const float n2  = norms[t2];
        const float b   = beta[labels[t0]];
        const float dap = sqrtf(fmaxf(n0 + n1 - 2.0f * v1.f, 0.0f) + EPS_);
        const float dan = sqrtf(fmaxf(n0 + n2 - 2.0f * v2.f, 0.0f) + EPS_);
        const float pos = fmaxf(dap - b + MARGIN, 0.0f);
        const float neg = fmaxf(b - dan + MARGIN, 0.0f);
        pn = pos + neg;
        c  = ((pos > 0.0f) || (neg > 0.0f)) ? 1 : 0;
    }
    #pragma unroll
    for (int off = 1; off < 64; off <<= 1) {
        pn += __shfl_xor(pn, off, 64);
        c  += __shfl_xor(c,  off, 64);
    }
    __shared__ float s_tot[4];
    __shared__ int   s_cnt[4];
    const int wid = threadIdx.x >> 6;
    if ((threadIdx.x & 63) == 0) { s_tot[wid] = pn; s_cnt[wid] = c; }
    __syncthreads();
    if (threadIdx.x == 0) {
        atomicAdd(ws_total, s_tot[0] + s_tot[1] + s_tot[2] + s_tot[3]);
        atomicAdd(ws_cnt, (unsigned)(s_cnt[0] + s_cnt[1] + s_cnt[2] + s_cnt[3]));
        __threadfence();
        const unsigned done = atomicAdd(ws_done, 1u);
        if (done == gridDim.x - 1) {
            const float    total = atomicAdd(ws_total, 0.0f);
            const unsigned pcnt  = atomicAdd(ws_cnt, 0u);
            const float pc = (float)pcnt;
            out[0] = (pc > 0.0f) ? (total / fmaxf(pc, 1.0f)) : total;
        }
    }
}

// ---------------------------------------------------------------------------
// Standalone fp32 fallback (any D % 4 == 0; needs only 8 B of ws).
// ---------------------------------------------------------------------------
__global__ __launch_bounds__(256) void triplet_loss_generic(
    const float* __restrict__ batch,
    const float* __restrict__ beta,
    const int*   __restrict__ labels,
    const int*   __restrict__ triplets,
    int T, int D,
    float*        __restrict__ ws_total,
    unsigned int* __restrict__ ws_cnt)
{
    const int lane   = threadIdx.x & 63;
    const int wid    = threadIdx.x >> 6;
    const int gwave  = (blockIdx.x * blockDim.x + threadIdx.x) >> 6;
    const int nwaves = (gridDim.x * blockDim.x) >> 6;
    const int dq     = D >> 2;

    float        tot = 0.0f;
    unsigned int cnt = 0u;

    for (int t = gwave; t < T; t += nwaves) {
        const int t0 = triplets[3 * t + 0];
        const int t1 = triplets[3 * t + 1];
        const int t2 = triplets[3 * t + 2];
        const float4* A = (const float4*)(batch + (size_t)t0 * D);
        const float4* P = (const float4*)(batch + (size_t)t1 * D);
        const float4* N = (const float4*)(batch + (size_t)t2 * D);
        float sap = 0.0f, san = 0.0f;
        for (int idx = lane; idx < dq; idx += 64) {
            const float4 av = A[idx];
            const float4 pv = P[idx];
            const float4 nv = N[idx];
            float dx = av.x - pv.x, dy = av.y - pv.y, dz = av.z - pv.z, dw = av.w - pv.w;
            sap += dx * dx + dy * dy + dz * dz + dw * dw;
            dx = av.x - nv.x; dy = av.y - nv.y; dz = av.z - nv.z; dw = av.w - nv.w;
            san += dx * dx + dy * dy + dz * dz + dw * dw;
        }
        #pragma unroll
        for (int off = 1; off < 64; off <<= 1) {
            sap += __shfl_xor(sap, off, 64);
            san += __shfl_xor(san, off, 64);
        }
        if (lane == 0) {
            const float d_ap = sqrtf(sap + EPS_);
            const float d_an = sqrtf(san + EPS_);
            const float b    = beta[labels[t0]];
            const float pos  = fmaxf(d_ap - b + MARGIN, 0.0f);
            const float neg  = fmaxf(b - d_an + MARGIN, 0.0f);
            tot += pos + neg;
            cnt += ((pos > 0.0f) || (neg > 0.0f)) ? 1u : 0u;
        }
    }

    __shared__ float        s_tot[4];
    __shared__ unsigned int s_cnt[4];
    if (lane == 0) { s_tot[wid] = tot; s_cnt[wid] = cnt; }
    __syncthreads();
    if (threadIdx.x == 0) {
        float        bt = 0.0f;
        unsigned int bc = 0u;
        const int nw = blockDim.x >> 6;
        for (int i = 0; i < nw; ++i) { bt += s_tot[i]; bc += s_cnt[i]; }
        atomicAdd(ws_total, bt);
        atomicAdd(ws_cnt, bc);
    }
}

__global__ void finalize_kernel(const float* __restrict__ ws_total,
                                const unsigned int* __restrict__ ws_cnt,
                                float* __restrict__ out)
{
    const float total = ws_total[0];
    const float pc    = (float)ws_cnt[0];
    out[0] = (pc > 0.0f) ? (total / fmaxf(pc, 1.0f)) : total;
}

extern "C" void kernel_launch(void* const* d_in, const int* in_sizes, int n_in,
                              void* d_out, int out_size, void* d_ws, size_t ws_size,
                              hipStream_t stream)
{
    const float* batch    = (const float*)d_in[0];
    const float* beta     = (const float*)d_in[1];
    const int*   labels   = (const int*)d_in[2];
    const int*   triplets = (const int*)d_in[3];

    const int B = in_sizes[2];            // 4096
    const int D = in_sizes[0] / B;        // 512
    const int T = in_sizes[3] / 3;        // 65536

    float*        ws_total = (float*)d_ws;
    unsigned int* ws_cnt   = (unsigned int*)((char*)d_ws + 4);
    unsigned int* ws_done  = (unsigned int*)((char*)d_ws + 8);

    // ws layout: [0,12) counters | norms at 4096 | G bf16 at 32768
    const size_t nm_off = 4096;
    const size_t g_off  = 32768;
    const size_t need   = g_off + (size_t)B * B * 2;

    const bool fast = (B % BM == 0) && (D % BKF == 0) && (ws_size >= need) &&
                      (T >= 1) && (nm_off + (size_t)B * 4 <= g_off);

    if (fast) {
        float*          norms = (float*)((char*)d_ws + nm_off);
        unsigned short* G     = (unsigned short*)((char*)d_ws + g_off);

        const int NB = B / BM;
        const int ntiles = NB * (NB + 1) / 2;     // 528 upper-tri blocks
        gemm_fused<<<ntiles, 256, 0, stream>>>(
            batch, G, norms, B, D, NB, ntiles, ws_total, ws_cnt, ws_done);

        tri_eval<<<(T + 255) / 256, 256, 0, stream>>>(
            G, norms, beta, labels, triplets, B, T,
            ws_total, ws_cnt, ws_done, (float*)d_out);
    } else {
        (void)hipMemsetAsync(d_ws, 0, 12, stream);
        const int block = 256;
        int grid = 2048;
        const int max_grid = (T + 3) / 4;
        if (grid > max_grid) grid = max_grid;
        triplet_loss_generic<<<grid, block, 0, stream>>>(
            batch, beta, labels, triplets, T, D, ws_total, ws_cnt);
        finalize_kernel<<<1, 1, 0, stream>>>(ws_total, ws_cnt, (float*)d_out);
    }
}

// Round 17
// 42.739 us; speedup vs baseline: 1.2599x; 1.2599x over previous
//
#include <hip/hip_runtime.h>

#define MARGIN 0.2f
#define EPS_    1e-8f
#define BM 128
#define BK 32             // bf16 K-step: 64 B per row-segment, 32 KB total LDS

typedef __attribute__((ext_vector_type(8))) short short8;
typedef __attribute__((ext_vector_type(4))) float f32x4;

// ---------------------------------------------------------------------------
// prep: fp32 -> bf16 (RNE) packed; fp32 row norms (wave g == row g at D=512);
// zero the 3 counter words.   (identical to R15)
// ---------------------------------------------------------------------------
__device__ __forceinline__ unsigned pack_bf16(float lo, float hi)
{
    union { float f; unsigned u; } a, b;
    a.f = lo; b.f = hi;
    unsigned ua = (a.u + 0x7fffu + ((a.u >> 16) & 1u)) >> 16;
    unsigned ub = (b.u + 0x7fffu + ((b.u >> 16) & 1u)) & 0xffff0000u;
    return ua | ub;
}

__device__ __forceinline__ unsigned short bf16_1(float x)
{
    union { float f; unsigned u; } v;
    v.f = x;
    return (unsigned short)((v.u + 0x7fffu + ((v.u >> 16) & 1u)) >> 16);
}

__global__ __launch_bounds__(256) void prep_kernel(
    const float* __restrict__ in, uint4* __restrict__ out, int n8,
    float* __restrict__ norms, int B,
    float* __restrict__ ws_total, unsigned int* __restrict__ ws_cnt,
    unsigned int* __restrict__ ws_done)
{
    const int i = blockIdx.x * blockDim.x + threadIdx.x;
    if (i == 0) { *ws_total = 0.0f; *ws_cnt = 0u; *ws_done = 0u; }
    float s = 0.0f;
    if (i < n8) {
        const float4 a = ((const float4*)in)[2 * i + 0];
        const float4 b = ((const float4*)in)[2 * i + 1];
        uint4 r;
        r.x = pack_bf16(a.x, a.y);
        r.y = pack_bf16(a.z, a.w);
        r.z = pack_bf16(b.x, b.y);
        r.w = pack_bf16(b.z, b.w);
        out[i] = r;
        s = a.x * a.x + a.y * a.y + a.z * a.z + a.w * a.w
          + b.x * b.x + b.y * b.y + b.z * b.z + b.w * b.w;
    }
    #pragma unroll
    for (int off = 1; off < 64; off <<= 1)
        s += __shfl_xor(s, off, 64);
    const int row = i >> 6;
    if ((threadIdx.x & 63) == 0 && row < B) norms[row] = s;
}

// ---------------------------------------------------------------------------
// G = X . X^T (bf16 in, bf16 out), upper-tri linear grid + XCD swizzle.
// BK=32 double-buffered = 32 KB LDS -> 4 blocks/CU -> all 528 blocks
// co-resident, NO TAIL (R16 profile showed the 2-block/CU tail cost).
// Counted vmcnt(4) pipeline (4 global_load_lds per wave per stage).
// Both-sides swizzle sigma(row) = (row&3)<<4 on 64 B rows (2-way max = free).
// G symmetric => transpose-class MFMA layout errors are output-invariant.
// ---------------------------------------------------------------------------
__global__ __launch_bounds__(256) void gemm_xxt(
    const char* __restrict__ xb,     // bf16 X, row stride D*2 bytes
    unsigned short* __restrict__ G, int B, int D, int NB, int ntiles)
{
    // bijective XCD swizzle (ntiles % 8 == 0 at B=4096)
    const int q = ntiles >> 3, r8 = ntiles & 7;
    const int xcd = blockIdx.x & 7, idx = blockIdx.x >> 3;
    int lin = ((xcd < r8) ? xcd * (q + 1) : r8 * (q + 1) + (xcd - r8) * q) + idx;

    int bm = 0, rowlen = NB;
    while (lin >= rowlen) { lin -= rowlen; ++bm; --rowlen; }
    const int bn = bm + lin;

    __shared__ char At[2][BM * BK * 2];        // 2 x 8 KB
    __shared__ char Bt[2][BM * BK * 2];        // 2 x 8 KB  -> 32 KB total
    const int tid  = threadIdx.x;
    const int lane = tid & 63;
    const int w    = tid >> 6;
    const int wr   = w >> 1, wc = w & 1;
    const int rowb = D * 2;
    const int l15  = lane & 15;
    const int hi   = lane >> 4;

    f32x4 acc[4][4] = {};

    // chunk c = 16 rows x 64 B = 1 KB; lane l handles row c*16+(l>>2),
    // inner 16 B slot (l&3)*16, global source pre-swizzled by sigma(row).
    const int lrow = lane >> 2;                 // row-in-chunk 0..15
    const int ssw  = ((lane & 3) * 16) ^ ((lrow & 3) << 4);

    auto stage = [&](int kk, int p) {
        #pragma unroll
        for (int c2 = 0; c2 < 2; ++c2) {
            const int c = w * 2 + c2;          // chunks 0..7
            const size_t arow = (size_t)bm * BM + c * 16 + lrow;
            const size_t brow = (size_t)bn * BM + c * 16 + lrow;
            const char* asrc = xb + arow * rowb + kk * (BK * 2) + ssw;
            const char* bsrc = xb + brow * rowb + kk * (BK * 2) + ssw;
            __builtin_amdgcn_global_load_lds((const unsigned*)asrc,
                (unsigned*)(At[p] + c * 1024 + lane * 16), 16, 0, 0);
            __builtin_amdgcn_global_load_lds((const unsigned*)bsrc,
                (unsigned*)(Bt[p] + c * 1024 + lane * 16), 16, 0, 0);
        }
    };

    const int rsw = (l15 & 3) << 4;            // sigma(row) for this lane's rows
    const int nk = D / BK;
    stage(0, 0);
    for (int kk = 0; kk < nk; ++kk) {
        const int p = kk & 1;
        if (kk + 1 < nk) {
            stage(kk + 1, p ^ 1);                              // 4/wave in flight
            asm volatile("s_waitcnt vmcnt(4)" ::: "memory");   // tile kk ready
        } else {
            asm volatile("s_waitcnt vmcnt(0)" ::: "memory");
        }
        __builtin_amdgcn_s_barrier();
        __builtin_amdgcn_sched_barrier(0);

        const int kbyte = (hi * 16) ^ rsw;
        short8 a[4], b[4];
        #pragma unroll
        for (int m = 0; m < 4; ++m) {
            const int row = wr * 64 + m * 16 + l15;
            a[m] = *(const short8*)(At[p] + row * 64 + kbyte);
        }
        #pragma unroll
        for (int n = 0; n < 4; ++n) {
            const int row = wc * 64 + n * 16 + l15;
            b[n] = *(const short8*)(Bt[p] + row * 64 + kbyte);
        }
        #pragma unroll
        for (int m = 0; m < 4; ++m)
            #pragma unroll
            for (int n = 0; n < 4; ++n)
                acc[m][n] = __builtin_amdgcn_mfma_f32_16x16x32_bf16(
                    a[m], b[n], acc[m][n], 0, 0, 0);

        asm volatile("s_waitcnt lgkmcnt(0)" ::: "memory");
        __builtin_amdgcn_sched_barrier(0);
        __builtin_amdgcn_s_barrier();
    }

    #pragma unroll
    for (int m = 0; m < 4; ++m)
        #pragma unroll
        for (int n = 0; n < 4; ++n)
            #pragma unroll
            for (int j = 0; j < 4; ++j) {
                const int row = bm * BM + wr * 64 + m * 16 + hi * 4 + j;
                const int col = bn * BM + wc * 64 + n * 16 + l15;
                G[(size_t)row * B + col] = bf16_1(acc[m][n][j]);
            }
}

// ---------------------------------------------------------------------------
// phase 2 + finalize: d^2 = n_i + n_j - 2 g_ij (fp32 norms, bf16 G);
// block-reduce + atomics; last block writes the loss.  (identical to R15)
// ---------------------------------------------------------------------------
__global__ __launch_bounds__(256) void tri_eval(
    const unsigned short* __restrict__ G,
    const float* __restrict__ norms,
    const float* __restrict__ beta,
    const int*   __restrict__ labels,
    const int*   __restrict__ trip,
    int B, int T,
    float*        __restrict__ ws_total,
    unsigned int* __restrict__ ws_cnt,
    unsigned int* __restrict__ ws_done,
    float*        __restrict__ out)
{
    const int i = blockIdx.x * blockDim.x + threadIdx.x;
    float pn = 0.0f;
    int   c  = 0;
    if (i < T) {
        const int t0 = trip[3 * i + 0];
        const int t1 = trip[3 * i + 1];
        const int t2 = trip[3 * i + 2];
        const int r1 = t0 < t1 ? t0 : t1, c1 = t0 < t1 ? t1 : t0;
        const int r2 = t0 < t2 ? t0 : t2, c2 = t0 < t2 ? t2 : t0;
        union { unsigned u; float f; } v1, v2;
        v1.u = (unsigned)G[(size_t)r1 * B + c1] << 16;
        v2.u = (unsigned)G[(size_t)r2 * B + c2] << 16;
        const float n0  = norms[t0];
        const float n1  = norms[t1];
        const float n2  = norms[t2];
        const float b   = beta[labels[t0]];
        const float dap = sqrtf(fmaxf(n0 + n1 - 2.0f * v1.f, 0.0f) + EPS_);
        const float dan = sqrtf(fmaxf(n0 + n2 - 2.0f * v2.f, 0.0f) + EPS_);
        const float pos = fmaxf(dap - b + MARGIN, 0.0f);
        const float neg = fmaxf(b - dan + MARGIN, 0.0f);
        pn = pos + neg;
        c  = ((pos > 0.0f) || (neg > 0.0f)) ? 1 : 0;
    }
    #pragma unroll
    for (int off = 1; off < 64; off <<= 1) {
        pn += __shfl_xor(pn, off, 64);
        c  += __shfl_xor(c,  off, 64);
    }
    __shared__ float s_tot[4];
    __shared__ int   s_cnt[4];
    const int wid = threadIdx.x >> 6;
    if ((threadIdx.x & 63) == 0) { s_tot[wid] = pn; s_cnt[wid] = c; }
    __syncthreads();
    if (threadIdx.x == 0) {
        atomicAdd(ws_total, s_tot[0] + s_tot[1] + s_tot[2] + s_tot[3]);
        atomicAdd(ws_cnt, (unsigned)(s_cnt[0] + s_cnt[1] + s_cnt[2] + s_cnt[3]));
        __threadfence();
        const unsigned done = atomicAdd(ws_done, 1u);
        if (done == gridDim.x - 1) {
            const float    total = atomicAdd(ws_total, 0.0f);
            const unsigned pcnt  = atomicAdd(ws_cnt, 0u);
            const float pc = (float)pcnt;
            out[0] = (pc > 0.0f) ? (total / fmaxf(pc, 1.0f)) : total;
        }
    }
}

// ---------------------------------------------------------------------------
// Standalone fp32 fallback (any D % 4 == 0; needs only 8 B of ws).
// ---------------------------------------------------------------------------
__global__ __launch_bounds__(256) void triplet_loss_generic(
    const float* __restrict__ batch,
    const float* __restrict__ beta,
    const int*   __restrict__ labels,
    const int*   __restrict__ triplets,
    int T, int D,
    float*        __restrict__ ws_total,
    unsigned int* __restrict__ ws_cnt)
{
    const int lane   = threadIdx.x & 63;
    const int wid    = threadIdx.x >> 6;
    const int gwave  = (blockIdx.x * blockDim.x + threadIdx.x) >> 6;
    const int nwaves = (gridDim.x * blockDim.x) >> 6;
    const int dq     = D >> 2;

    float        tot = 0.0f;
    unsigned int cnt = 0u;

    for (int t = gwave; t < T; t += nwaves) {
        const int t0 = triplets[3 * t + 0];
        const int t1 = triplets[3 * t + 1];
        const int t2 = triplets[3 * t + 2];
        const float4* A = (const float4*)(batch + (size_t)t0 * D);
        const float4* P = (const float4*)(batch + (size_t)t1 * D);
        const float4* N = (const float4*)(batch + (size_t)t2 * D);
        float sap = 0.0f, san = 0.0f;
        for (int idx = lane; idx < dq; idx += 64) {
            const float4 av = A[idx];
            const float4 pv = P[idx];
            const float4 nv = N[idx];
            float dx = av.x - pv.x, dy = av.y - pv.y, dz = av.z - pv.z, dw = av.w - pv.w;
            sap += dx * dx + dy * dy + dz * dz + dw * dw;
            dx = av.x - nv.x; dy = av.y - nv.y; dz = av.z - nv.z; dw = av.w - nv.w;
            san += dx * dx + dy * dy + dz * dz + dw * dw;
        }
        #pragma unroll
        for (int off = 1; off < 64; off <<= 1) {
            sap += __shfl_xor(sap, off, 64);
            san += __shfl_xor(san, off, 64);
        }
        if (lane == 0) {
            const float d_ap = sqrtf(sap + EPS_);
            const float d_an = sqrtf(san + EPS_);
            const float b    = beta[labels[t0]];
            const float pos  = fmaxf(d_ap - b + MARGIN, 0.0f);
            const float neg  = fmaxf(b - d_an + MARGIN, 0.0f);
            tot += pos + neg;
            cnt += ((pos > 0.0f) || (neg > 0.0f)) ? 1u : 0u;
        }
    }

    __shared__ float        s_tot[4];
    __shared__ unsigned int s_cnt[4];
    if (lane == 0) { s_tot[wid] = tot; s_cnt[wid] = cnt; }
    __syncthreads();
    if (threadIdx.x == 0) {
        float        bt = 0.0f;
        unsigned int bc = 0u;
        const int nw = blockDim.x >> 6;
        for (int i = 0; i < nw; ++i) { bt += s_tot[i]; bc += s_cnt[i]; }
        atomicAdd(ws_total, bt);
        atomicAdd(ws_cnt, bc);
    }
}

__global__ void finalize_kernel(const float* __restrict__ ws_total,
                                const unsigned int* __restrict__ ws_cnt,
                                float* __restrict__ out)
{
    const float total = ws_total[0];
    const float pc    = (float)ws_cnt[0];
    out[0] = (pc > 0.0f) ? (total / fmaxf(pc, 1.0f)) : total;
}

extern "C" void kernel_launch(void* const* d_in, const int* in_sizes, int n_in,
                              void* d_out, int out_size, void* d_ws, size_t ws_size,
                              hipStream_t stream)
{
    const float* batch    = (const float*)d_in[0];
    const float* beta     = (const float*)d_in[1];
    const int*   labels   = (const int*)d_in[2];
    const int*   triplets = (const int*)d_in[3];

    const int B = in_sizes[2];            // 4096
    const int D = in_sizes[0] / B;        // 512
    const int T = in_sizes[3] / 3;        // 65536

    float*        ws_total = (float*)d_ws;
    unsigned int* ws_cnt   = (unsigned int*)((char*)d_ws + 4);
    unsigned int* ws_done  = (unsigned int*)((char*)d_ws + 8);

    // ws layout: [0,12) counters | norms at 4096 | X bf16 at 32768 | G bf16
    const size_t nm_off = 4096;
    const size_t hb_off = 32768;
    const size_t g_off  = (hb_off + (size_t)B * D * 2 + 255) & ~(size_t)255;
    const size_t need   = g_off + (size_t)B * B * 2;

    const bool fast = (B % BM == 0) && (D == 512) && (ws_size >= need) &&
                      (T >= 1) && (nm_off + (size_t)B * 4 <= hb_off);

    if (fast) {
        float*          norms = (float*)((char*)d_ws + nm_off);
        uint4*          hb    = (uint4*)((char*)d_ws + hb_off);
        unsigned short* G     = (unsigned short*)((char*)d_ws + g_off);

        const int n8 = (B * D) / 8;
        prep_kernel<<<(n8 + 255) / 256, 256, 0, stream>>>(
            batch, hb, n8, norms, B, ws_total, ws_cnt, ws_done);

        const int NB = B / BM;
        const int ntiles = NB * (NB + 1) / 2;     // 528 upper-tri blocks
        gemm_xxt<<<ntiles, 256, 0, stream>>>(
            (const char*)hb, G, B, D, NB, ntiles);

        tri_eval<<<(T + 255) / 256, 256, 0, stream>>>(
            G, norms, beta, labels, triplets, B, T,
            ws_total, ws_cnt, ws_done, (float*)d_out);
    } else {
        (void)hipMemsetAsync(d_ws, 0, 12, stream);
        const int block = 256;
        int grid = 2048;
        const int max_grid = (T + 3) / 4;
        if (grid > max_grid) grid = max_grid;
        triplet_loss_generic<<<grid, block, 0, stream>>>(
            batch, beta, labels, triplets, T, D, ws_total, ws_cnt);
        finalize_kernel<<<1, 1, 0, stream>>>(ws_total, ws_cnt, (float*)d_out);
    }
}